// Round 5
// baseline (1641.641 us; speedup 1.0000x reference)
//
#include <hip/hip_runtime.h>

// Problem constants
#define V_  32000
#define E_  256
#define H_  256
#define S_  128
#define B_  64
#define HID_ 30

typedef float f32x2 __attribute__((ext_vector_type(2)));

// Accurate f32 activations
__device__ __forceinline__ float sigmoid_acc(float x) {
    return 1.0f / (1.0f + expf(-x));
}
__device__ __forceinline__ float tanh_acc(float x) {
    return tanhf(x);
}

// ---------------------------------------------------------------------------
// K1: f32 input-projection GEMM with fused embedding gather.
//   Xg[dir][m][g] = sum_k emb[concepts[m]][k] * Wih[g][k],  m = s*64+b
// 128x128 tile, 8x8 per thread, KC=32 via LDS. grid (512, 2), block 256.
// ---------------------------------------------------------------------------
#define GKC 32
#define GLD 132   // LDS row stride

__global__ __launch_bounds__(256, 4) void gemm2_kernel(
    const int* __restrict__ concepts, const float* __restrict__ embedding,
    const float* __restrict__ Wih_f, const float* __restrict__ Wih_b,
    float* __restrict__ Xg) {
    __shared__ float As[GKC][GLD];   // [k][m]
    __shared__ float Bs[GKC][GLD];   // [k][g]
    const int dir = blockIdx.y;
    const float* Wih = dir ? Wih_b : Wih_f;
    const int mt = blockIdx.x >> 3;      // 0..63
    const int nt = blockIdx.x & 7;       // 0..7
    const int m0 = mt * 128, n0 = nt * 128;
    const int t = threadIdx.x;
    const int tm = (t & 15) * 4;
    const int tn = (t >> 4) * 4;

    // hoist gather ids (constant across k-chunks)
    int cid[4];
    int rr[4];
#pragma unroll
    for (int i = 0; i < 4; ++i) {
        int flat = t + 256 * i;
        rr[i] = flat >> 3;
        cid[i] = concepts[m0 + rr[i]];
    }

    float acc[8][8];
#pragma unroll
    for (int i = 0; i < 8; ++i)
#pragma unroll
        for (int j = 0; j < 8; ++j) acc[i][j] = 0.f;

    for (int kk = 0; kk < E_; kk += GKC) {
        __syncthreads();
#pragma unroll
        for (int i = 0; i < 4; ++i) {
            int flat = t + 256 * i;
            int r = rr[i];
            int kq = (flat & 7) * 4;
            float4 av = *(const float4*)&embedding[(size_t)cid[i] * E_ + kk + kq];
            float4 bv = *(const float4*)&Wih[(size_t)(n0 + r) * E_ + kk + kq];
            As[kq + 0][r] = av.x; As[kq + 1][r] = av.y;
            As[kq + 2][r] = av.z; As[kq + 3][r] = av.w;
            Bs[kq + 0][r] = bv.x; Bs[kq + 1][r] = bv.y;
            Bs[kq + 2][r] = bv.z; Bs[kq + 3][r] = bv.w;
        }
        __syncthreads();
#pragma unroll
        for (int k = 0; k < GKC; ++k) {
            float4 a0 = *(const float4*)&As[k][tm];
            float4 a1 = *(const float4*)&As[k][tm + 64];
            float4 b0 = *(const float4*)&Bs[k][tn];
            float4 b1 = *(const float4*)&Bs[k][tn + 64];
            float am[8] = {a0.x, a0.y, a0.z, a0.w, a1.x, a1.y, a1.z, a1.w};
            float bn[8] = {b0.x, b0.y, b0.z, b0.w, b1.x, b1.y, b1.z, b1.w};
#pragma unroll
            for (int i = 0; i < 8; ++i)
#pragma unroll
                for (int j = 0; j < 8; ++j)
                    acc[i][j] = fmaf(am[i], bn[j], acc[i][j]);
        }
    }
    float* out = Xg + ((size_t)dir * 8192 + m0) * 1024 + n0;
#pragma unroll
    for (int i = 0; i < 8; ++i) {
        int mr = (i < 4) ? (tm + i) : (tm + 60 + i);   // tm+i or tm+64+(i-4)
        *(float4*)&out[(size_t)mr * 1024 + tn] =
            make_float4(acc[i][0], acc[i][1], acc[i][2], acc[i][3]);
        *(float4*)&out[(size_t)mr * 1024 + tn + 64] =
            make_float4(acc[i][4], acc[i][5], acc[i][6], acc[i][7]);
    }
}

// ---------------------------------------------------------------------------
// K2: LSTM, unit-split halves with h-exchange. 256 WGs x 512 thr (1/CU),
// both dirs concurrent, cooperative launch.
// WG = (b, dir, side): owns units [128*side, 128*side+128), i.e. the FULL
// 512 gate rows of those units. Thread t: gate gt=t>>7, unit ul=t&127,
// row = gt*256 + side*128 + ul; full 256-col dot:
//   own-half cols: 58 pairs in regs + 6 pairs in LDS  (h local)
//   partner cols:  32 pairs in regs + 32 pairs in LDS (h from partner WG)
// Partner h is published as packed (tag<<32|f32) relaxed agent atomics at
// finalize time; the poll is overlapped with the own-half dot.
// ---------------------------------------------------------------------------
#define OWN_REG 58
#define OWN_LDS 6
#define PAR_REG 32
#define PAR_LDS 32
#define NSLOT (OWN_LDS + PAR_LDS)   // 38 pair-columns in LDS

__global__ __launch_bounds__(512, 2) void lstm_half_kernel(
    const float* __restrict__ Xg,     // [2][8192][1024]
    const float* __restrict__ Whh_f, const float* __restrict__ Whh_b,
    const float* __restrict__ b_f, const float* __restrict__ b_b,
    const int* __restrict__ lens,
    float* __restrict__ enc,          // [B][S][512]
    unsigned long long* __restrict__ Xch) {  // [P=128][2 par][2 side][128]
    extern __shared__ f32x2 Wl[];     // [NSLOT][512]
    __shared__ f32x2 h_sh2[128];      // full h as 128 pairs
    __shared__ float g_sh[4][128];
    const int wg = blockIdx.x;        // 0..255
    const int side = wg & 1;
    const int P = wg >> 1;            // 0..127
    const int dir = P & 1, b = P >> 1;
    const int t = threadIdx.x;        // 0..511
    const int gt = t >> 7, ul = t & 127;
    const int row = (gt << 8) + (side << 7) + ul;   // gate row 0..1023
    const int obase = side << 7;      // own col base
    const int pbase = obase ^ 128;    // partner col base
    const float* Whh = dir ? Whh_b : Whh_f;
    const int len = lens[b];

    // --- pin weights: regs + LDS ---
    f32x2 wO[OWN_REG], wP[PAR_REG];
    {
        const f32x2* wr = (const f32x2*)(Whh + (size_t)row * H_);
        const f32x2* ow = wr + (obase >> 1);
        const f32x2* pw = wr + (pbase >> 1);
#pragma unroll
        for (int j = 0; j < OWN_REG; ++j) wO[j] = ow[j];
#pragma unroll
        for (int j = 0; j < PAR_REG; ++j) wP[j] = pw[j];
#pragma unroll
        for (int j = 0; j < OWN_LDS; ++j) Wl[j * 512 + t] = ow[OWN_REG + j];
#pragma unroll
        for (int j = 0; j < PAR_LDS; ++j)
            Wl[(OWN_LDS + j) * 512 + t] = pw[PAR_REG + j];
    }
    const float bias = (dir ? b_b : b_f)[row];

    if (t < 128) h_sh2[t] = (f32x2){0.f, 0.f};
    float c = 0.f;                    // cell state (gt==0 threads)
    __syncthreads();

    int srow = dir ? (len - 1) : 0;   // len >= 1 guaranteed
    float xv = Xg[((size_t)dir * 8192 + (size_t)srow * B_ + b) * 1024 + row];

    for (int s = 0; s < S_; ++s) {
        // next-step x prefetch
        int srow_n = 0;
        float xv_n = 0.f;
        if (s + 1 < S_) {
            int ns = s + 1;
            srow_n = dir ? ((ns < len) ? (len - 1 - ns) : ns) : ns;
            xv_n = Xg[((size_t)dir * 8192 + (size_t)srow_n * B_ + b) * 1024 + row];
        }

        // A: own-half dot (h local; partner h in flight meanwhile)
        f32x2 a = (f32x2){0.f, 0.f};
        const f32x2* ho = h_sh2 + (obase >> 1);
#pragma unroll
        for (int j = 0; j < OWN_REG; ++j)
            a = __builtin_elementwise_fma(wO[j], ho[j], a);
#pragma unroll
        for (int j = 0; j < OWN_LDS; ++j)
            a = __builtin_elementwise_fma(Wl[j * 512 + t], ho[OWN_REG + j], a);

        // B: poll partner h(s)  (tag s, parity s&1; memset-0 == tag0,h=0)
        if (t < 128) {
            unsigned long long v;
            unsigned long long* ps =
                Xch + (((size_t)P * 2 + (s & 1)) * 2 + (side ^ 1)) * 128 + t;
            do {
                v = __hip_atomic_load(ps, __ATOMIC_RELAXED,
                                      __HIP_MEMORY_SCOPE_AGENT);
            } while ((unsigned)(v >> 32) != (unsigned)s);
            ((float*)h_sh2)[pbase + t] = __uint_as_float((unsigned)v);
        }
        __syncthreads();   // #1: partner h in LDS

        // C: partner-half dot
        const f32x2* hp = h_sh2 + (pbase >> 1);
#pragma unroll
        for (int j = 0; j < PAR_REG; ++j)
            a = __builtin_elementwise_fma(wP[j], hp[j], a);
#pragma unroll
        for (int j = 0; j < PAR_LDS; ++j)
            a = __builtin_elementwise_fma(Wl[(OWN_LDS + j) * 512 + t],
                                          hp[PAR_REG + j], a);
        float gate = a.x + a.y + bias + xv;
        g_sh[gt][ul] = (gt == 2) ? tanh_acc(gate) : sigmoid_acc(gate);
        __syncthreads();   // #2: gates ready; h fully consumed

        // D: finalize units (gt==0 threads), write enc, publish h(s+1)
        if (t < 128) {
            float iv = g_sh[0][ul], fv = g_sh[1][ul];
            float gg = g_sh[2][ul], ov = g_sh[3][ul];
            c = fv * c + iv * gg;
            float h = ov * tanh_acc(c);
            ((float*)h_sh2)[obase + ul] = h;
            int orow = dir ? srow : s;
            enc[((size_t)b * S_ + orow) * 512 + dir * H_ + obase + ul] =
                (orow < len) ? h : 0.f;
            if (s + 1 < S_) {
                unsigned long long pk =
                    ((unsigned long long)(unsigned)(s + 1) << 32) |
                    (unsigned long long)__float_as_uint(h);
                __hip_atomic_store(
                    Xch + (((size_t)P * 2 + ((s + 1) & 1)) * 2 + side) * 128 + ul,
                    pk, __ATOMIC_RELAXED, __HIP_MEMORY_SCOPE_AGENT);
            }
        }
        __syncthreads();   // #3: own h ready for next step's A

        srow = srow_n;
        xv = xv_n;
    }
}

// ---------------------------------------------------------------------------
// K3: U = enc@Ua^T, W = enc@Wa^T
// ---------------------------------------------------------------------------
__global__ __launch_bounds__(256) void uw_kernel(
    const float* __restrict__ enc, const float* __restrict__ Ua,
    const float* __restrict__ Wa, float* __restrict__ U, float* __restrict__ Wout) {
    __shared__ float wgt[60][129];
    __shared__ float erow[4][128];
    const int tid = threadIdx.x;
    const int b = blockIdx.y, s0 = blockIdx.x * 32;
    const int rl = tid >> 6;
    const int d = tid & 63;
    const int dd = d & 31;
    const int isW = d >> 5;
    float acc[8];
#pragma unroll
    for (int i = 0; i < 8; ++i) acc[i] = 0.f;

    for (int kk = 0; kk < 4; ++kk) {
        __syncthreads();
        for (int i = tid; i < 30 * 128; i += 256) {
            int r = i >> 7, k = i & 127;
            wgt[r][k] = Ua[(size_t)r * 512 + kk * 128 + k];
            wgt[r + 30][k] = Wa[(size_t)r * 512 + kk * 128 + k];
        }
        for (int chunk = 0; chunk < 8; ++chunk) {
            __syncthreads();
            for (int i = tid; i < 4 * 128; i += 256) {
                int r = i >> 7, k = i & 127;
                erow[r][k] = enc[((size_t)b * S_ + (s0 + chunk * 4 + r)) * 512 + kk * 128 + k];
            }
            __syncthreads();
            if (dd < HID_) {
                const float* wr = wgt[dd + 30 * isW];
                const float* er = erow[rl];
                float a = acc[chunk];
#pragma unroll
                for (int k = 0; k < 128; ++k) a = fmaf(er[k], wr[k], a);
                acc[chunk] = a;
            }
        }
    }
    if (dd < HID_) {
        float* dst = isW ? Wout : U;
#pragma unroll
        for (int chunk = 0; chunk < 8; ++chunk)
            dst[((size_t)b * S_ + (s0 + chunk * 4 + rl)) * 32 + dd] = acc[chunk];
    }
}

// ---------------------------------------------------------------------------
// K4: scores + predictions
// ---------------------------------------------------------------------------
__global__ __launch_bounds__(256) void scores_kernel(
    const float* __restrict__ U, const float* __restrict__ W,
    const float* __restrict__ va,
    float* __restrict__ scores, float* __restrict__ preds) {
    __shared__ float w_sh[128][31];
    const int b = blockIdx.y, i0 = blockIdx.x * 32;
    const int tid = threadIdx.x;

    float va_r[HID_];
#pragma unroll
    for (int d2 = 0; d2 < HID_; ++d2) va_r[d2] = va[d2];

    for (int i = tid; i < 128 * HID_; i += 256) {
        int r = i / HID_, d2 = i - r * HID_;
        w_sh[r][d2] = W[((size_t)b * S_ + r) * 32 + d2];
    }
    __syncthreads();

    const int il = tid >> 3;
    const int jb = (tid & 7) * 16;
    float u_r[HID_];
    const float* urow = U + ((size_t)b * S_ + i0 + il) * 32;
#pragma unroll
    for (int d2 = 0; d2 < HID_; ++d2) u_r[d2] = urow[d2];

    const size_t obase = ((size_t)b * S_ + (i0 + il)) * S_;
    for (int jj = 0; jj < 16; ++jj) {
        int j = jb + jj;
        float acc = 0.f;
#pragma unroll
        for (int d2 = 0; d2 < HID_; ++d2)
            acc = fmaf(va_r[d2], tanh_acc(u_r[d2] + w_sh[j][d2]), acc);
        scores[obase + j] = acc;
        preds[obase + j] = (sigmoid_acc(acc) >= 0.5f) ? 1.f : 0.f;
    }
}

// ---------------------------------------------------------------------------
// Workspace layout (bytes):
//   Xg   @ 0          : 2*8192*1024*4 = 67,108,864
//   enc  @ 67,108,864 : 64*128*512*4  = 16,777,216
//   U    @ 83,886,080 : 8192*32*4     =  1,048,576
//   W    @ 84,934,656 : 8192*32*4     =  1,048,576
//   Xch  @ 85,983,232 : 128*2*2*128*8 =    524,288   (total ~86.5 MB)
// ---------------------------------------------------------------------------
extern "C" void kernel_launch(void* const* d_in, const int* in_sizes, int n_in,
                              void* d_out, int out_size, void* d_ws, size_t ws_size,
                              hipStream_t stream) {
    (void)in_sizes; (void)n_in; (void)out_size; (void)ws_size;
    const int* concepts = (const int*)d_in[0];
    const int* lens = (const int*)d_in[1];
    const float* embedding = (const float*)d_in[2];
    const float* Wih_f = (const float*)d_in[3];
    const float* Whh_f = (const float*)d_in[4];
    const float* b_f = (const float*)d_in[5];
    const float* Wih_b = (const float*)d_in[6];
    const float* Whh_b = (const float*)d_in[7];
    const float* b_b = (const float*)d_in[8];
    const float* Ua = (const float*)d_in[9];
    const float* Wa = (const float*)d_in[10];
    const float* va = (const float*)d_in[11];

    char* ws = (char*)d_ws;
    float* Xg = (float*)(ws + 0);
    float* enc = (float*)(ws + 67108864);
    float* U = (float*)(ws + 83886080);
    float* W = (float*)(ws + 84934656);
    unsigned long long* Xch = (unsigned long long*)(ws + 85983232);

    float* scores = (float*)d_out;
    float* preds = scores + (size_t)B_ * S_ * S_;

    // zero handoff slots: packed(tag=0, h=0.0f) == initial state h(0)=0
    hipMemsetAsync(Xch, 0, 524288, stream);

    hipLaunchKernelGGL(gemm2_kernel, dim3(512, 2), dim3(256), 0, stream,
                       concepts, embedding, Wih_f, Wih_b, Xg);

    {
        const float* XgA = Xg;
        void* ka[] = {(void*)&XgA, (void*)&Whh_f, (void*)&Whh_b, (void*)&b_f,
                      (void*)&b_b, (void*)&lens, (void*)&enc, (void*)&Xch};
        hipLaunchCooperativeKernel((const void*)lstm_half_kernel, dim3(256),
                                   dim3(512), ka,
                                   NSLOT * 512 * sizeof(f32x2), stream);
    }

    hipLaunchKernelGGL(uw_kernel, dim3(4, 64), dim3(256), 0, stream,
                       enc, Ua, Wa, U, W);
    hipLaunchKernelGGL(scores_kernel, dim3(4, 64), dim3(256), 0, stream,
                       U, W, va, scores, preds);
}